// Round 1
// 389.969 us; speedup vs baseline: 1.0297x; 1.0297x over previous
//
#include <hip/hip_runtime.h>

// EquivariantGraphConvCheap: N=50000, E=500000, H=128.
// R5: FUSE aggregate+transform. The split version round-tripped the fp32
//     aggregate through HBM (102 MB write + 102 MB read) and left transform
//     latency-bound (MfmaUtil 5.4%, VALUBusy 6.8%, HBM 25% -- all idle).
//     Now: per 32-node block, 4 waves aggregate 8 nodes each (fp32 acc,
//     RNE->bf16) into a 32 KB XOR-swizzled LDS tile; one barrier; then the
//     32x32x16 bf16 MFMA reads root-x from preloaded regs and agg from LDS.

typedef short bfrag __attribute__((ext_vector_type(8)));   // 8 bf16 = 4 VGPR
typedef float cfrag __attribute__((ext_vector_type(16)));  // 32x32 C/D tile

__device__ __forceinline__ short f2bf(float f) {
    unsigned u = __builtin_bit_cast(unsigned, f);
    u += 0x7fff + ((u >> 16) & 1);          // RNE
    return (short)(u >> 16);
}
__device__ __forceinline__ float bf2f(short s) {
    unsigned u = ((unsigned)(unsigned short)s) << 16;
    return __builtin_bit_cast(float, u);
}
__device__ __forceinline__ bfrag pack8(float4 lo, float4 hi) {
    bfrag r;
    r[0] = f2bf(lo.x); r[1] = f2bf(lo.y); r[2] = f2bf(lo.z); r[3] = f2bf(lo.w);
    r[4] = f2bf(hi.x); r[5] = f2bf(hi.y); r[6] = f2bf(hi.z); r[7] = f2bf(hi.w);
    return r;
}

// ---------- CSR build ----------
__global__ __launch_bounds__(256) void hist_kernel(
    const int* __restrict__ ei, int* __restrict__ counts, int E)
{
    int e = blockIdx.x * 256 + threadIdx.x;
    if (e < E) atomicAdd(&counts[ei[e]], 1);
}

__global__ __launch_bounds__(1024) void scan_local_kernel(
    const int* __restrict__ counts, int* __restrict__ offsets,
    int* __restrict__ blocksums, int N)
{
    __shared__ int wsum[16];
    const int tid = threadIdx.x, lane = tid & 63, wid = tid >> 6;
    int i = blockIdx.x * 1024 + tid;
    int v = (i < N) ? counts[i] : 0;
    int incl = v;
    #pragma unroll
    for (int off = 1; off < 64; off <<= 1) {
        int t = __shfl_up(incl, off, 64);
        if (lane >= off) incl += t;
    }
    if (lane == 63) wsum[wid] = incl;
    __syncthreads();
    if (wid == 0) {
        int ws = (lane < 16) ? wsum[lane] : 0;
        int wincl = ws;
        #pragma unroll
        for (int off = 1; off < 16; off <<= 1) {
            int t = __shfl_up(wincl, off, 64);
            if (lane >= off) wincl += t;
        }
        if (lane < 16) wsum[lane] = wincl - ws;
    }
    __syncthreads();
    int excl = incl - v + wsum[wid];
    if (i < N) offsets[i] = excl;
    if (tid == 1023) blocksums[blockIdx.x] = excl + v;
}

__global__ __launch_bounds__(64) void scan_blocksums_kernel(
    int* __restrict__ bs, int nb)
{
    int lane = threadIdx.x;
    int v = (lane < nb) ? bs[lane] : 0;
    int incl = v;
    #pragma unroll
    for (int off = 1; off < 64; off <<= 1) {
        int t = __shfl_up(incl, off, 64);
        if (lane >= off) incl += t;
    }
    if (lane < nb) bs[lane] = incl - v;
}

__global__ __launch_bounds__(1024) void scan_add_kernel(
    int* __restrict__ offsets, int* __restrict__ cursor,
    const int* __restrict__ bs, int N, int E)
{
    int i = blockIdx.x * 1024 + threadIdx.x;
    if (i < N) {
        int v = offsets[i] + bs[blockIdx.x];
        offsets[i] = v;
        cursor[i] = v;
    }
    if (i == 0) offsets[N] = E;
}

__global__ __launch_bounds__(256) void bin_kernel(
    const int* __restrict__ ei, int* __restrict__ cursor,
    int* __restrict__ bins, int E)
{
    int e = blockIdx.x * 256 + threadIdx.x;
    if (e < E) {
        int row = ei[e], col = ei[E + e];
        int pos = atomicAdd(&cursor[row], 1);
        bins[pos] = col;
    }
}

// ---------- conversions ----------
__global__ __launch_bounds__(256) void conv_x_kernel(
    const float* __restrict__ x, short* __restrict__ xbf, long long total8)
{
    long long i = (long long)blockIdx.x * 256 + threadIdx.x;
    if (i >= total8) return;
    float4 lo = *(const float4*)(x + i * 8);
    float4 hi = *(const float4*)(x + i * 8 + 4);
    *(bfrag*)(xbf + i * 8) = pack8(lo, hi);
}

// wbf layout: [Ws_root | Ws_rel | Wv_root | Wv_rel], each 128x128 row-major [o][h]
__global__ __launch_bounds__(256) void conv_w_kernel(
    const float* __restrict__ w0, const float* __restrict__ w1,
    const float* __restrict__ w2, const float* __restrict__ w3,
    short* __restrict__ wbf)
{
    int i = blockIdx.x * 256 + threadIdx.x;   // 0..8191
    int j = i * 8;
    int m = j >> 14, off = j & 16383;
    const float* src = (m == 0) ? w0 : (m == 1) ? w1 : (m == 2) ? w2 : w3;
    float4 lo = *(const float4*)(src + off);
    float4 hi = *(const float4*)(src + off + 4);
    *(bfrag*)(wbf + j) = pack8(lo, hi);
}

// ---------- fused aggregate + MFMA transform ----------
// block = 32 nodes, 256 threads = 4 waves.
// Phase A: wave w aggregates local nodes m = w*8..w*8+7 (all 64 lanes span the
//   node's 512 elems, lane*8), fp32 acc, RNE->bf16, write into swizzled LDS:
//   byte = m*1024 + ch*256 + ((slot*16) ^ ((m&15)<<4)).  The XOR is an
//   involution within each 256 B channel row; read applies the same XOR.
// Phase B: wave = channel c (0=scalar Ws, 1..3 vector Wv).
//   D[32x128] = Xroot[32x128]@Wroot^T + Agg[32x128]@Wrel^T (+bias c==0)
//   A-frag (32x32x16): A[m=lane&31][k=(lane>>5)*8+j]; B-frag: W[o=lane&31][k].
//   C/D: col=lane&31, row=(reg&3)+8*(reg>>2)+4*(lane>>5)  [measured m74/m101].
template<int XBF>
__global__ __launch_bounds__(256) void fused_agg_mfma(
    const float* __restrict__ x, const short* __restrict__ xbf,
    const int* __restrict__ offsets, const int* __restrict__ bins,
    float* __restrict__ out, const short* __restrict__ wbf,
    const float* __restrict__ b_s, int Nn)
{
    __shared__ short atile[32 * 512];   // 32 KB swizzled bf16 [m][ch][k]
    const int tid  = threadIdx.x;
    const int wid  = tid >> 6;
    const int lane = tid & 63;
    const int n0   = blockIdx.x * 32;

    // ---- Phase A: aggregate 8 nodes per wave into LDS ----
    const int cl   = lane >> 4;         // channel covered by this lane
    const int slot = lane & 15;         // 16B slot within the channel row
    #pragma unroll 1
    for (int i = 0; i < 8; i++) {
        const int m = wid * 8 + i;
        const int n = n0 + m;
        float acc[8] = {0, 0, 0, 0, 0, 0, 0, 0};
        if (n < Nn) {
            const int beg = offsets[n], end = offsets[n + 1];
            int e = beg;
            for (; e + 4 <= end; e += 4) {
                int c0 = bins[e], c1 = bins[e + 1], c2 = bins[e + 2], c3 = bins[e + 3];
                if (XBF) {
                    bfrag v0 = *(const bfrag*)(xbf + (size_t)c0 * 512 + lane * 8);
                    bfrag v1 = *(const bfrag*)(xbf + (size_t)c1 * 512 + lane * 8);
                    bfrag v2 = *(const bfrag*)(xbf + (size_t)c2 * 512 + lane * 8);
                    bfrag v3 = *(const bfrag*)(xbf + (size_t)c3 * 512 + lane * 8);
                    #pragma unroll
                    for (int j = 0; j < 8; j++)
                        acc[j] += (bf2f(v0[j]) + bf2f(v1[j])) + (bf2f(v2[j]) + bf2f(v3[j]));
                } else {
                    float4 l0 = *(const float4*)(x + (size_t)c0 * 512 + lane * 8);
                    float4 h0 = *(const float4*)(x + (size_t)c0 * 512 + lane * 8 + 4);
                    float4 l1 = *(const float4*)(x + (size_t)c1 * 512 + lane * 8);
                    float4 h1 = *(const float4*)(x + (size_t)c1 * 512 + lane * 8 + 4);
                    float4 l2 = *(const float4*)(x + (size_t)c2 * 512 + lane * 8);
                    float4 h2 = *(const float4*)(x + (size_t)c2 * 512 + lane * 8 + 4);
                    float4 l3 = *(const float4*)(x + (size_t)c3 * 512 + lane * 8);
                    float4 h3 = *(const float4*)(x + (size_t)c3 * 512 + lane * 8 + 4);
                    acc[0] += (l0.x + l1.x) + (l2.x + l3.x);
                    acc[1] += (l0.y + l1.y) + (l2.y + l3.y);
                    acc[2] += (l0.z + l1.z) + (l2.z + l3.z);
                    acc[3] += (l0.w + l1.w) + (l2.w + l3.w);
                    acc[4] += (h0.x + h1.x) + (h2.x + h3.x);
                    acc[5] += (h0.y + h1.y) + (h2.y + h3.y);
                    acc[6] += (h0.z + h1.z) + (h2.z + h3.z);
                    acc[7] += (h0.w + h1.w) + (h2.w + h3.w);
                }
            }
            for (; e < end; e++) {
                int cc = bins[e];
                if (XBF) {
                    bfrag v = *(const bfrag*)(xbf + (size_t)cc * 512 + lane * 8);
                    #pragma unroll
                    for (int j = 0; j < 8; j++) acc[j] += bf2f(v[j]);
                } else {
                    float4 l = *(const float4*)(x + (size_t)cc * 512 + lane * 8);
                    float4 h = *(const float4*)(x + (size_t)cc * 512 + lane * 8 + 4);
                    acc[0] += l.x; acc[1] += l.y; acc[2] += l.z; acc[3] += l.w;
                    acc[4] += h.x; acc[5] += h.y; acc[6] += h.z; acc[7] += h.w;
                }
            }
        }
        const int boff = m * 1024 + cl * 256 + ((slot * 16) ^ ((m & 15) << 4));
        *(bfrag*)((char*)atile + boff) =
            pack8(make_float4(acc[0], acc[1], acc[2], acc[3]),
                  make_float4(acc[4], acc[5], acc[6], acc[7]));
    }

    // ---- preload root-x fragments (independent of LDS; hides under barrier) ----
    const int c   = wid;                 // wave = channel
    const int l31 = lane & 31;
    const int kg  = lane >> 5;           // k-group 0/1
    int mA = n0 + l31; if (mA >= Nn) mA = Nn - 1;   // clamped A-row node
    const size_t arow = ((size_t)mA * 4 + c) * 128;
    bfrag a0[8];
    #pragma unroll
    for (int ks = 0; ks < 8; ks++) {
        const int k0 = ks * 16 + kg * 8;
        if (XBF) {
            a0[ks] = *(const bfrag*)(xbf + arow + k0);
        } else {
            float4 lo = *(const float4*)(x + arow + k0);
            float4 hi = *(const float4*)(x + arow + k0 + 4);
            a0[ks] = pack8(lo, hi);
        }
    }

    __syncthreads();

    // ---- Phase B: MFMA ----
    const short* wroot = wbf + ((c == 0) ? 0 : 2) * 16384;
    const short* wrel  = wbf + ((c == 0) ? 1 : 3) * 16384;

    cfrag acc4[4];
    #pragma unroll
    for (int t = 0; t < 4; t++)
        #pragma unroll
        for (int r = 0; r < 16; r++) acc4[t][r] = 0.f;

    #pragma unroll
    for (int ks = 0; ks < 8; ks++) {
        const int k0 = ks * 16 + kg * 8;
        // agg A-frag from swizzled LDS (node = l31, channel = c)
        const int rboff = l31 * 1024 + c * 256 + ((k0 * 2) ^ ((l31 & 15) << 4));
        bfrag a1 = *(const bfrag*)((const char*)atile + rboff);
        #pragma unroll
        for (int t = 0; t < 4; t++) {
            bfrag b0 = *(const bfrag*)(wroot + (size_t)(t * 32 + l31) * 128 + k0);
            acc4[t] = __builtin_amdgcn_mfma_f32_32x32x16_bf16(a0[ks], b0, acc4[t], 0, 0, 0);
            bfrag b1 = *(const bfrag*)(wrel + (size_t)(t * 32 + l31) * 128 + k0);
            acc4[t] = __builtin_amdgcn_mfma_f32_32x32x16_bf16(a1, b1, acc4[t], 0, 0, 0);
        }
    }

    float bv[4] = {0.f, 0.f, 0.f, 0.f};
    if (c == 0) {
        #pragma unroll
        for (int t = 0; t < 4; t++) bv[t] = b_s[t * 32 + l31];
    }

    #pragma unroll
    for (int t = 0; t < 4; t++) {
        #pragma unroll
        for (int r = 0; r < 16; r++) {
            int row = (r & 3) + 8 * (r >> 2) + 4 * kg;
            int node = n0 + row;
            if (node < Nn)
                out[((size_t)node * 4 + c) * 128 + t * 32 + l31] = acc4[t][r] + bv[t];
        }
    }
}

extern "C" void kernel_launch(void* const* d_in, const int* in_sizes, int n_in,
                              void* d_out, int out_size, void* d_ws, size_t ws_size,
                              hipStream_t stream) {
    const float* x        = (const float*)d_in[0];
    const int*   ei       = (const int*)d_in[1];
    const float* W_s_rel  = (const float*)d_in[2];
    const float* W_s_root = (const float*)d_in[3];
    const float* b_s_root = (const float*)d_in[4];
    const float* W_v_rel  = (const float*)d_in[5];
    const float* W_v_root = (const float*)d_in[6];
    float* out = (float*)d_out;

    int N = in_sizes[0] / 512;   // 50000
    int E = in_sizes[1] / 2;     // 500000

    // ws layout: wbf[65536 shorts] | (xbf[N*512 shorts] if it fits) | ints:
    //   counts[N] offsets[N+1] cursor[N] bins[E] blocksums[64]
    size_t ints_bytes = ((size_t)(3 * N + 1) + E + 64) * sizeof(int);
    size_t wbf_bytes  = 65536 * sizeof(short);
    size_t xbf_bytes  = (size_t)N * 512 * sizeof(short);
    bool use_bf = (ws_size >= wbf_bytes + xbf_bytes + ints_bytes);

    short* wbf = (short*)d_ws;
    short* xbf = wbf + 65536;
    int* counts = use_bf ? (int*)(xbf + (size_t)N * 512) : (int*)xbf;
    int* offsets   = counts + N;
    int* cursor    = offsets + N + 1;
    int* bins      = cursor + N;
    int* blocksums = bins + E;

    int nb = (N + 1023) / 1024;

    hipMemsetAsync(counts, 0, (size_t)N * sizeof(int), stream);
    hist_kernel<<<(E + 255) / 256, 256, 0, stream>>>(ei, counts, E);
    scan_local_kernel<<<nb, 1024, 0, stream>>>(counts, offsets, blocksums, N);
    scan_blocksums_kernel<<<1, 64, 0, stream>>>(blocksums, nb);
    scan_add_kernel<<<nb, 1024, 0, stream>>>(offsets, cursor, blocksums, N, E);
    bin_kernel<<<(E + 255) / 256, 256, 0, stream>>>(ei, cursor, bins, E);

    conv_w_kernel<<<32, 256, 0, stream>>>(W_s_root, W_s_rel, W_v_root, W_v_rel, wbf);

    if (use_bf) {
        long long total8 = (long long)N * 64;   // N*512/8
        conv_x_kernel<<<(int)((total8 + 255) / 256), 256, 0, stream>>>(x, xbf, total8);
        fused_agg_mfma<1><<<(N + 31) / 32, 256, 0, stream>>>(
            x, xbf, offsets, bins, out, wbf, b_s_root, N);
    } else {
        fused_agg_mfma<0><<<(N + 31) / 32, 256, 0, stream>>>(
            x, nullptr, offsets, bins, out, wbf, b_s_root, N);
    }
}

// Round 2
// 384.833 us; speedup vs baseline: 1.0434x; 1.0133x over previous
//
#include <hip/hip_runtime.h>

// EquivariantGraphConvCheap: N=50000, E=500000, H=128.
// R6: attack the gather. R5 showed FETCH=258MB on a 51MB-resident gather set
//     (L3 thrashed by conv_x's 102MB x-stream and out's 100MB write-allocate)
//     and only 4 loads in flight per wave (latency-bound: MfmaUtil 3.3%,
//     VALUBusy 15.6%, HBM 29%).
//     Fixes: (1) non-temporal loads of x in conv_x + non-temporal stores of
//     out in the epilogue, keeping xbf hot in L3; (2) 8-deep gather unroll
//     (8/4/1 chunks) to double outstanding misses per wave.

typedef short bfrag __attribute__((ext_vector_type(8)));   // 8 bf16 = 4 VGPR
typedef float cfrag __attribute__((ext_vector_type(16)));  // 32x32 C/D tile
typedef float f4v  __attribute__((ext_vector_type(4)));    // for NT load

__device__ __forceinline__ short f2bf(float f) {
    unsigned u = __builtin_bit_cast(unsigned, f);
    u += 0x7fff + ((u >> 16) & 1);          // RNE
    return (short)(u >> 16);
}
__device__ __forceinline__ float bf2f(short s) {
    unsigned u = ((unsigned)(unsigned short)s) << 16;
    return __builtin_bit_cast(float, u);
}
__device__ __forceinline__ bfrag pack8(float4 lo, float4 hi) {
    bfrag r;
    r[0] = f2bf(lo.x); r[1] = f2bf(lo.y); r[2] = f2bf(lo.z); r[3] = f2bf(lo.w);
    r[4] = f2bf(hi.x); r[5] = f2bf(hi.y); r[6] = f2bf(hi.z); r[7] = f2bf(hi.w);
    return r;
}
__device__ __forceinline__ bfrag pack8v(f4v lo, f4v hi) {
    bfrag r;
    r[0] = f2bf(lo[0]); r[1] = f2bf(lo[1]); r[2] = f2bf(lo[2]); r[3] = f2bf(lo[3]);
    r[4] = f2bf(hi[0]); r[5] = f2bf(hi[1]); r[6] = f2bf(hi[2]); r[7] = f2bf(hi[3]);
    return r;
}

// ---------- CSR build ----------
__global__ __launch_bounds__(256) void hist_kernel(
    const int* __restrict__ ei, int* __restrict__ counts, int E)
{
    int e = blockIdx.x * 256 + threadIdx.x;
    if (e < E) atomicAdd(&counts[ei[e]], 1);
}

__global__ __launch_bounds__(1024) void scan_local_kernel(
    const int* __restrict__ counts, int* __restrict__ offsets,
    int* __restrict__ blocksums, int N)
{
    __shared__ int wsum[16];
    const int tid = threadIdx.x, lane = tid & 63, wid = tid >> 6;
    int i = blockIdx.x * 1024 + tid;
    int v = (i < N) ? counts[i] : 0;
    int incl = v;
    #pragma unroll
    for (int off = 1; off < 64; off <<= 1) {
        int t = __shfl_up(incl, off, 64);
        if (lane >= off) incl += t;
    }
    if (lane == 63) wsum[wid] = incl;
    __syncthreads();
    if (wid == 0) {
        int ws = (lane < 16) ? wsum[lane] : 0;
        int wincl = ws;
        #pragma unroll
        for (int off = 1; off < 16; off <<= 1) {
            int t = __shfl_up(wincl, off, 64);
            if (lane >= off) wincl += t;
        }
        if (lane < 16) wsum[lane] = wincl - ws;
    }
    __syncthreads();
    int excl = incl - v + wsum[wid];
    if (i < N) offsets[i] = excl;
    if (tid == 1023) blocksums[blockIdx.x] = excl + v;
}

__global__ __launch_bounds__(64) void scan_blocksums_kernel(
    int* __restrict__ bs, int nb)
{
    int lane = threadIdx.x;
    int v = (lane < nb) ? bs[lane] : 0;
    int incl = v;
    #pragma unroll
    for (int off = 1; off < 64; off <<= 1) {
        int t = __shfl_up(incl, off, 64);
        if (lane >= off) incl += t;
    }
    if (lane < nb) bs[lane] = incl - v;
}

__global__ __launch_bounds__(1024) void scan_add_kernel(
    int* __restrict__ offsets, int* __restrict__ cursor,
    const int* __restrict__ bs, int N, int E)
{
    int i = blockIdx.x * 1024 + threadIdx.x;
    if (i < N) {
        int v = offsets[i] + bs[blockIdx.x];
        offsets[i] = v;
        cursor[i] = v;
    }
    if (i == 0) offsets[N] = E;
}

__global__ __launch_bounds__(256) void bin_kernel(
    const int* __restrict__ ei, int* __restrict__ cursor,
    int* __restrict__ bins, int E)
{
    int e = blockIdx.x * 256 + threadIdx.x;
    if (e < E) {
        int row = ei[e], col = ei[E + e];
        int pos = atomicAdd(&cursor[row], 1);
        bins[pos] = col;
    }
}

// ---------- conversions ----------
// NT loads: x is read exactly once here (XBF path never re-reads fp32 x),
// so don't let its 102 MB evict xbf from L3.
__global__ __launch_bounds__(256) void conv_x_kernel(
    const float* __restrict__ x, short* __restrict__ xbf, long long total8)
{
    long long i = (long long)blockIdx.x * 256 + threadIdx.x;
    if (i >= total8) return;
    f4v lo = __builtin_nontemporal_load((const f4v*)(x + i * 8));
    f4v hi = __builtin_nontemporal_load((const f4v*)(x + i * 8 + 4));
    *(bfrag*)(xbf + i * 8) = pack8v(lo, hi);
}

// wbf layout: [Ws_root | Ws_rel | Wv_root | Wv_rel], each 128x128 row-major [o][h]
__global__ __launch_bounds__(256) void conv_w_kernel(
    const float* __restrict__ w0, const float* __restrict__ w1,
    const float* __restrict__ w2, const float* __restrict__ w3,
    short* __restrict__ wbf)
{
    int i = blockIdx.x * 256 + threadIdx.x;   // 0..8191
    int j = i * 8;
    int m = j >> 14, off = j & 16383;
    const float* src = (m == 0) ? w0 : (m == 1) ? w1 : (m == 2) ? w2 : w3;
    float4 lo = *(const float4*)(src + off);
    float4 hi = *(const float4*)(src + off + 4);
    *(bfrag*)(wbf + j) = pack8(lo, hi);
}

// ---------- fused aggregate + MFMA transform ----------
// block = 32 nodes, 256 threads = 4 waves.
// Phase A: wave w aggregates local nodes m = w*8..w*8+7 (all 64 lanes span the
//   node's 512 elems, lane*8), fp32 acc, RNE->bf16, write into swizzled LDS:
//   byte = m*1024 + ch*256 + ((slot*16) ^ ((m&15)<<4)).  The XOR is an
//   involution within each 256 B channel row; read applies the same XOR.
//   Gather is 8-deep (8 independent 16B loads in flight), then 4, then 1.
// Phase B: wave = channel c (0=scalar Ws, 1..3 vector Wv).
//   D[32x128] = Xroot[32x128]@Wroot^T + Agg[32x128]@Wrel^T (+bias c==0)
//   A-frag (32x32x16): A[m=lane&31][k=(lane>>5)*8+j]; B-frag: W[o=lane&31][k].
//   C/D: col=lane&31, row=(reg&3)+8*(reg>>2)+4*(lane>>5)  [measured m74/m101].
// Epilogue: non-temporal stores (out never re-read; don't evict xbf).
template<int XBF>
__global__ __launch_bounds__(256) void fused_agg_mfma(
    const float* __restrict__ x, const short* __restrict__ xbf,
    const int* __restrict__ offsets, const int* __restrict__ bins,
    float* __restrict__ out, const short* __restrict__ wbf,
    const float* __restrict__ b_s, int Nn)
{
    __shared__ short atile[32 * 512];   // 32 KB swizzled bf16 [m][ch][k]
    const int tid  = threadIdx.x;
    const int wid  = tid >> 6;
    const int lane = tid & 63;
    const int n0   = blockIdx.x * 32;

    // ---- Phase A: aggregate 8 nodes per wave into LDS ----
    const int cl   = lane >> 4;         // channel covered by this lane
    const int slot = lane & 15;         // 16B slot within the channel row
    #pragma unroll 1
    for (int i = 0; i < 8; i++) {
        const int m = wid * 8 + i;
        const int n = n0 + m;
        float acc[8] = {0, 0, 0, 0, 0, 0, 0, 0};
        if (n < Nn) {
            const int beg = offsets[n], end = offsets[n + 1];
            int e = beg;
            if (XBF) {
                for (; e + 8 <= end; e += 8) {
                    int cc[8];
                    #pragma unroll
                    for (int q = 0; q < 8; q++) cc[q] = bins[e + q];
                    bfrag v[8];
                    #pragma unroll
                    for (int q = 0; q < 8; q++)
                        v[q] = *(const bfrag*)(xbf + (size_t)cc[q] * 512 + lane * 8);
                    #pragma unroll
                    for (int j = 0; j < 8; j++)
                        acc[j] += ((bf2f(v[0][j]) + bf2f(v[1][j])) +
                                   (bf2f(v[2][j]) + bf2f(v[3][j]))) +
                                  ((bf2f(v[4][j]) + bf2f(v[5][j])) +
                                   (bf2f(v[6][j]) + bf2f(v[7][j])));
                }
                for (; e + 4 <= end; e += 4) {
                    int cc[4];
                    #pragma unroll
                    for (int q = 0; q < 4; q++) cc[q] = bins[e + q];
                    bfrag v[4];
                    #pragma unroll
                    for (int q = 0; q < 4; q++)
                        v[q] = *(const bfrag*)(xbf + (size_t)cc[q] * 512 + lane * 8);
                    #pragma unroll
                    for (int j = 0; j < 8; j++)
                        acc[j] += (bf2f(v[0][j]) + bf2f(v[1][j])) +
                                  (bf2f(v[2][j]) + bf2f(v[3][j]));
                }
                for (; e < end; e++) {
                    int cc = bins[e];
                    bfrag v = *(const bfrag*)(xbf + (size_t)cc * 512 + lane * 8);
                    #pragma unroll
                    for (int j = 0; j < 8; j++) acc[j] += bf2f(v[j]);
                }
            } else {
                for (; e < end; e++) {
                    int cc = bins[e];
                    float4 l = *(const float4*)(x + (size_t)cc * 512 + lane * 8);
                    float4 h = *(const float4*)(x + (size_t)cc * 512 + lane * 8 + 4);
                    acc[0] += l.x; acc[1] += l.y; acc[2] += l.z; acc[3] += l.w;
                    acc[4] += h.x; acc[5] += h.y; acc[6] += h.z; acc[7] += h.w;
                }
            }
        }
        const int boff = m * 1024 + cl * 256 + ((slot * 16) ^ ((m & 15) << 4));
        *(bfrag*)((char*)atile + boff) =
            pack8(make_float4(acc[0], acc[1], acc[2], acc[3]),
                  make_float4(acc[4], acc[5], acc[6], acc[7]));
    }

    // ---- preload root-x fragments (independent of LDS; hides under barrier) ----
    const int c   = wid;                 // wave = channel
    const int l31 = lane & 31;
    const int kg  = lane >> 5;           // k-group 0/1
    int mA = n0 + l31; if (mA >= Nn) mA = Nn - 1;   // clamped A-row node
    const size_t arow = ((size_t)mA * 4 + c) * 128;
    bfrag a0[8];
    #pragma unroll
    for (int ks = 0; ks < 8; ks++) {
        const int k0 = ks * 16 + kg * 8;
        if (XBF) {
            a0[ks] = *(const bfrag*)(xbf + arow + k0);
        } else {
            float4 lo = *(const float4*)(x + arow + k0);
            float4 hi = *(const float4*)(x + arow + k0 + 4);
            a0[ks] = pack8(lo, hi);
        }
    }

    __syncthreads();

    // ---- Phase B: MFMA ----
    const short* wroot = wbf + ((c == 0) ? 0 : 2) * 16384;
    const short* wrel  = wbf + ((c == 0) ? 1 : 3) * 16384;

    cfrag acc4[4];
    #pragma unroll
    for (int t = 0; t < 4; t++)
        #pragma unroll
        for (int r = 0; r < 16; r++) acc4[t][r] = 0.f;

    #pragma unroll
    for (int ks = 0; ks < 8; ks++) {
        const int k0 = ks * 16 + kg * 8;
        // agg A-frag from swizzled LDS (node = l31, channel = c)
        const int rboff = l31 * 1024 + c * 256 + ((k0 * 2) ^ ((l31 & 15) << 4));
        bfrag a1 = *(const bfrag*)((const char*)atile + rboff);
        #pragma unroll
        for (int t = 0; t < 4; t++) {
            bfrag b0 = *(const bfrag*)(wroot + (size_t)(t * 32 + l31) * 128 + k0);
            acc4[t] = __builtin_amdgcn_mfma_f32_32x32x16_bf16(a0[ks], b0, acc4[t], 0, 0, 0);
            bfrag b1 = *(const bfrag*)(wrel + (size_t)(t * 32 + l31) * 128 + k0);
            acc4[t] = __builtin_amdgcn_mfma_f32_32x32x16_bf16(a1, b1, acc4[t], 0, 0, 0);
        }
    }

    float bv[4] = {0.f, 0.f, 0.f, 0.f};
    if (c == 0) {
        #pragma unroll
        for (int t = 0; t < 4; t++) bv[t] = b_s[t * 32 + l31];
    }

    #pragma unroll
    for (int t = 0; t < 4; t++) {
        #pragma unroll
        for (int r = 0; r < 16; r++) {
            int row = (r & 3) + 8 * (r >> 2) + 4 * kg;
            int node = n0 + row;
            if (node < Nn)
                __builtin_nontemporal_store(
                    acc4[t][r] + bv[t],
                    out + ((size_t)node * 4 + c) * 128 + t * 32 + l31);
        }
    }
}

extern "C" void kernel_launch(void* const* d_in, const int* in_sizes, int n_in,
                              void* d_out, int out_size, void* d_ws, size_t ws_size,
                              hipStream_t stream) {
    const float* x        = (const float*)d_in[0];
    const int*   ei       = (const int*)d_in[1];
    const float* W_s_rel  = (const float*)d_in[2];
    const float* W_s_root = (const float*)d_in[3];
    const float* b_s_root = (const float*)d_in[4];
    const float* W_v_rel  = (const float*)d_in[5];
    const float* W_v_root = (const float*)d_in[6];
    float* out = (float*)d_out;

    int N = in_sizes[0] / 512;   // 50000
    int E = in_sizes[1] / 2;     // 500000

    // ws layout: wbf[65536 shorts] | (xbf[N*512 shorts] if it fits) | ints:
    //   counts[N] offsets[N+1] cursor[N] bins[E] blocksums[64]
    size_t ints_bytes = ((size_t)(3 * N + 1) + E + 64) * sizeof(int);
    size_t wbf_bytes  = 65536 * sizeof(short);
    size_t xbf_bytes  = (size_t)N * 512 * sizeof(short);
    bool use_bf = (ws_size >= wbf_bytes + xbf_bytes + ints_bytes);

    short* wbf = (short*)d_ws;
    short* xbf = wbf + 65536;
    int* counts = use_bf ? (int*)(xbf + (size_t)N * 512) : (int*)xbf;
    int* offsets   = counts + N;
    int* cursor    = offsets + N + 1;
    int* bins      = cursor + N;
    int* blocksums = bins + E;

    int nb = (N + 1023) / 1024;

    hipMemsetAsync(counts, 0, (size_t)N * sizeof(int), stream);
    hist_kernel<<<(E + 255) / 256, 256, 0, stream>>>(ei, counts, E);
    scan_local_kernel<<<nb, 1024, 0, stream>>>(counts, offsets, blocksums, N);
    scan_blocksums_kernel<<<1, 64, 0, stream>>>(blocksums, nb);
    scan_add_kernel<<<nb, 1024, 0, stream>>>(offsets, cursor, blocksums, N, E);
    bin_kernel<<<(E + 255) / 256, 256, 0, stream>>>(ei, cursor, bins, E);

    conv_w_kernel<<<32, 256, 0, stream>>>(W_s_root, W_s_rel, W_v_root, W_v_rel, wbf);

    if (use_bf) {
        long long total8 = (long long)N * 64;   // N*512/8
        conv_x_kernel<<<(int)((total8 + 255) / 256), 256, 0, stream>>>(x, xbf, total8);
        fused_agg_mfma<1><<<(N + 31) / 32, 256, 0, stream>>>(
            x, xbf, offsets, bins, out, wbf, b_s_root, N);
    } else {
        fused_agg_mfma<0><<<(N + 31) / 32, 256, 0, stream>>>(
            x, nullptr, offsets, bins, out, wbf, b_s_root, N);
    }
}